// Round 7
// baseline (141.720 us; speedup 1.0000x reference)
//
#include <hip/hip_runtime.h>

// B=4, C=256, CR=64, H=W=64, K=7, KK=49, GROUPS=16, GC=16
#define BN_EPS 1e-5f

typedef __bf16 bf16_t;
typedef __bf16 bf16x8 __attribute__((ext_vector_type(8)));
typedef __bf16 bf16x4 __attribute__((ext_vector_type(4)));
typedef __bf16 bf16x2 __attribute__((ext_vector_type(2)));
typedef float  floatx4 __attribute__((ext_vector_type(4)));

#define MFMA16(a, b, c) __builtin_amdgcn_mfma_f32_16x16x32_bf16((a), (b), (c), 0, 0, 0)

// ws layout: only xT (16384 px x 64 ch bf16 = 2 MB)
#define XT_OFF 0

// ---------------------------------------------------------------------------
// K1 conv1: one block per (b,h), 512 threads (2 waves/SIMD). w1 A-frags direct
// from global (L2-hot) with BN fold in regs; guide transpose staged in LDS.
// MFMA x[64o][64p]; +bias, ReLU; store xT[bp][o] (c-contiguous).
// ---------------------------------------------------------------------------
#define GTP 264

__global__ __launch_bounds__(512) void conv1_k(
    const float* __restrict__ guide, const float* __restrict__ w1,
    const float* __restrict__ gamma, const float* __restrict__ beta,
    const float* __restrict__ mean,  const float* __restrict__ var,
    bf16_t* __restrict__ xT)
{
    __shared__ __attribute__((aligned(16))) bf16_t gTs[64 * GTP];  // 33.8 KB
    const int b = blockIdx.x >> 6, h = blockIdx.x & 63;
    const int t = threadIdx.x;

    // stage guide row transposed: coalesced dword reads (lanes = p)
    const float* gsrc = guide + (size_t)b * 256 * 4096 + h * 64;
#pragma unroll
    for (int i = 0; i < 16; ++i) {
        const int idx = i * 512 + t;       // 8192 units = 128 c2 x 64 p
        const int c2 = idx >> 6, p = idx & 63;
        const float g0 = gsrc[(size_t)(2 * c2) * 4096 + p];
        const float g1 = gsrc[(size_t)(2 * c2 + 1) * 4096 + p];
        bf16x2 pk; pk[0] = (bf16_t)g0; pk[1] = (bf16_t)g1;
        *(bf16x2*)&gTs[p * GTP + 2 * c2] = pk;
    }
    __syncthreads();

    const int wv = t >> 6, ln = t & 63, l15 = ln & 15, q = ln >> 4;
    const int ot = wv & 3;          // o-tile: channels ot*16 .. +16
    const int ph = wv >> 2;         // p-half: pixels ph*32 .. +32
    const int o = ot * 16 + l15;    // A-row this lane reads
    const float iv = gamma[o] * rsqrtf(var[o] + BN_EPS);

    floatx4 acc[2] = {};
#pragma unroll
    for (int ks = 0; ks < 8; ++ks) {
        const float* wp = w1 + o * 256 + ks * 32 + q * 8;
        const float4 a0 = *(const float4*)(wp);
        const float4 a1 = *(const float4*)(wp + 4);
        bf16x8 a;
        a[0] = (bf16_t)(a0.x * iv); a[1] = (bf16_t)(a0.y * iv);
        a[2] = (bf16_t)(a0.z * iv); a[3] = (bf16_t)(a0.w * iv);
        a[4] = (bf16_t)(a1.x * iv); a[5] = (bf16_t)(a1.y * iv);
        a[6] = (bf16_t)(a1.z * iv); a[7] = (bf16_t)(a1.w * iv);
#pragma unroll
        for (int nt = 0; nt < 2; ++nt) {
            const bf16x8 bb = *(const bf16x8*)&gTs[(ph * 32 + nt * 16 + l15) * GTP + ks * 32 + q * 8];
            acc[nt] = MFMA16(a, bb, acc[nt]);
        }
    }
    float bi[4];
#pragma unroll
    for (int j = 0; j < 4; ++j) {
        const int o2 = ot * 16 + q * 4 + j;
        const float iv2 = gamma[o2] * rsqrtf(var[o2] + BN_EPS);
        bi[j] = beta[o2] - mean[o2] * iv2;
    }
#pragma unroll
    for (int nt = 0; nt < 2; ++nt) {
        const int p = ph * 32 + nt * 16 + l15;
        bf16x4 v;
#pragma unroll
        for (int j = 0; j < 4; ++j) v[j] = (bf16_t)fmaxf(acc[nt][j] + bi[j], 0.f);
        *(bf16x4*)(xT + ((size_t)(b * 64 + h) * 64 + p) * 64 + ot * 16 + q * 4) = v;
    }
}

// ---------------------------------------------------------------------------
// K2 conv2+agg fused, h-OCT blocks + software pipeline: block = (g, b, h-oct),
// grid 512 (fully co-resident at 2 blocks/CU: no sequential block rounds).
// Loop 4 h-pairs with double-buffered wgs (only LDS, 2x13.3 KB):
//   prologue: compute_wg(pair0 -> buf0); barrier
//   iter p:   agg(pair p) from wgs[p&1]  [long VALU stream],
//             compute_wg(pair p+1 -> other buf)  [its xT/w2 loads hoist into
//             the agg stream; MFMA pipe overlaps VALU pipe], barrier.
// Feature taps: direct global, depth-2 register pipeline (no fs LDS; L2
// absorption proven in R5). Predicated quads reproduce zero-padding;
// residual reloaded from center quad (L1-hot). No min-waves launch bound.
// XCD = g%8 -> per-XCD feat slice ~2.1 MB + xT 2 MB, L2-resident.
// ---------------------------------------------------------------------------
#define WGP 136    // wgs row pitch (bf16)

__global__ __launch_bounds__(256) void fused_k(
    const bf16_t* __restrict__ xT, const float* __restrict__ w2,
    const float* __restrict__ b2,  const float* __restrict__ feat,
    float* __restrict__ out)
{
    __shared__ __attribute__((aligned(16))) bf16_t wgs[2][49 * WGP];  // 26.7 KB

    const int g = blockIdx.x & 15;
    const int rest = blockIdx.x >> 4;      // 0..31
    const int b = rest >> 3, oct = rest & 7;
    const int hbase = oct * 8;
    const int t = threadIdx.x;
    const int wv = t >> 6, ln = t & 63, l15 = ln & 15, q = ln >> 4;

    // agg thread mapping
    const int wq = t & 15, r = (t >> 4) & 1, cp = t >> 5;   // cp in [0,8)
    const int w0 = wq * 4;
    const int ch0 = cp * 2;
    const bool q0v = (w0 > 0);      // quad at w0-4 valid
    const bool q2v = (w0 < 60);     // quad at w0+4 valid
    const float* fbase = feat + ((size_t)(b * 256 + g * 16 + ch0) * 64) * 64;

    // ---- compute_wg: MFMA wg[49 x 128] for rows (h0,h0+1) into wgs[buf] ----
    auto compute_wg = [&](int h0, int buf) {
        floatx4 acc[4][2] = {};
        const bf16_t* brow = xT + ((size_t)(b * 64 + h0) * 64 + wv * 32) * 64;
#pragma unroll
        for (int ks = 0; ks < 2; ++ks) {
            bf16x8 bfr[2];
            bfr[0] = *(const bf16x8*)(brow + l15 * 64 + ks * 32 + q * 8);
            bfr[1] = *(const bf16x8*)(brow + (16 + l15) * 64 + ks * 32 + q * 8);
#pragma unroll
            for (int mt = 0; mt < 4; ++mt) {
                int row = mt * 16 + l15; if (row > 48) row = 48;  // pad rows never stored
                const float* wp = w2 + (size_t)(g * 49 + row) * 64 + ks * 32 + q * 8;
                const float4 a0 = *(const float4*)(wp);
                const float4 a1 = *(const float4*)(wp + 4);
                bf16x8 a;
                a[0] = (bf16_t)a0.x; a[1] = (bf16_t)a0.y; a[2] = (bf16_t)a0.z; a[3] = (bf16_t)a0.w;
                a[4] = (bf16_t)a1.x; a[5] = (bf16_t)a1.y; a[6] = (bf16_t)a1.z; a[7] = (bf16_t)a1.w;
                acc[mt][0] = MFMA16(a, bfr[0], acc[mt][0]);
                acc[mt][1] = MFMA16(a, bfr[1], acc[mt][1]);
            }
        }
#pragma unroll
        for (int mt = 0; mt < 4; ++mt) {
#pragma unroll
            for (int j = 0; j < 4; ++j) {
                const int k = mt * 16 + q * 4 + j;
                if (k < 49) {
                    const float bias = b2[g * 49 + k];
                    wgs[buf][k * WGP + wv * 32 + l15]      = (bf16_t)(acc[mt][0][j] + bias);
                    wgs[buf][k * WGP + wv * 32 + 16 + l15] = (bf16_t)(acc[mt][1][j] + bias);
                }
            }
        }
    };

    // ---- agg for rows (h0,h0+1) reading wgs[buf]; feat direct from global ----
    auto do_agg = [&](int h0, int buf) {
#define LOAD_STAGE(di, WA, FA, FB) do {                                        \
        const bf16_t* wrow_ = &wgs[buf][((di) * 7) * WGP + r * 64 + w0];       \
        _Pragma("unroll")                                                      \
        for (int dj = 0; dj < 7; ++dj) WA[dj] = *(const bf16x4*)(wrow_ + dj * WGP); \
        const int hh_ = h0 + r + (di) - 3;                                     \
        const bool rv_ = (hh_ >= 0) && (hh_ < 64);                             \
        const float* f0_ = fbase + (ptrdiff_t)hh_ * 64;                        \
        const float* f1_ = f0_ + 4096;                                         \
        FA[0] = (floatx4){0.f,0.f,0.f,0.f}; FB[0] = FA[0];                     \
        FA[1] = FA[0]; FB[1] = FA[0]; FA[2] = FA[0]; FB[2] = FA[0];            \
        if (rv_ && q0v) { FA[0] = *(const floatx4*)(f0_ + w0 - 4);             \
                          FB[0] = *(const floatx4*)(f1_ + w0 - 4); }           \
        if (rv_)        { FA[1] = *(const floatx4*)(f0_ + w0);                 \
                          FB[1] = *(const floatx4*)(f1_ + w0); }               \
        if (rv_ && q2v) { FA[2] = *(const floatx4*)(f0_ + w0 + 4);             \
                          FB[2] = *(const floatx4*)(f1_ + w0 + 4); }           \
    } while (0)

#define FMA_STAGE(WA, FA, FB) do {                                             \
        _Pragma("unroll")                                                      \
        for (int dj = 0; dj < 7; ++dj) {                                       \
            const bf16x4 wb_ = WA[dj];                                         \
            _Pragma("unroll")                                                  \
            for (int x = 0; x < 4; ++x) {                                      \
                const int e = x + dj + 1;                                      \
                const float wf_ = (float)wb_[x];                               \
                acc[0][x] = fmaf(wf_, FA[e >> 2][e & 3], acc[0][x]);           \
                acc[1][x] = fmaf(wf_, FB[e >> 2][e & 3], acc[1][x]);           \
            }                                                                  \
        }                                                                      \
    } while (0)

        float acc[2][4] = {};
        bf16x4 waA[7], waB[7];
        floatx4 faA[3], fbA[3], faB[3], fbB[3];

        LOAD_STAGE(0, waA, faA, fbA);
        LOAD_STAGE(1, waB, faB, fbB);
        FMA_STAGE(waA, faA, fbA);
        LOAD_STAGE(2, waA, faA, fbA);
        FMA_STAGE(waB, faB, fbB);
        LOAD_STAGE(3, waB, faB, fbB);
        FMA_STAGE(waA, faA, fbA);
        LOAD_STAGE(4, waA, faA, fbA);
        FMA_STAGE(waB, faB, fbB);
        LOAD_STAGE(5, waB, faB, fbB);
        FMA_STAGE(waA, faA, fbA);
        LOAD_STAGE(6, waA, faA, fbA);
        FMA_STAGE(waB, faB, fbB);
        FMA_STAGE(waA, faA, fbA);

#undef LOAD_STAGE
#undef FMA_STAGE

        // residual: reload center quad (row h0+r always valid; L1/L2-hit) + store
#pragma unroll
        for (int c = 0; c < 2; ++c) {
            const floatx4 res = *(const floatx4*)(fbase + (size_t)c * 4096 + (h0 + r) * 64 + w0);
            const size_t ob = ((size_t)(b * 256 + g * 16 + ch0 + c) * 64 + h0 + r) * 64 + w0;
            float4 o;
            o.x = acc[c][0] + res[0]; o.y = acc[c][1] + res[1];
            o.z = acc[c][2] + res[2]; o.w = acc[c][3] + res[3];
            *(float4*)(out + ob) = o;
        }
    };

    // ---- pipelined main loop over 4 h-pairs ----
    compute_wg(hbase, 0);
    __syncthreads();
#pragma unroll
    for (int p = 0; p < 4; ++p) {
        const int h0 = hbase + p * 2;
        do_agg(h0, p & 1);
        if (p < 3) {
            compute_wg(h0 + 2, (p + 1) & 1);
            __syncthreads();
        }
    }
}

extern "C" void kernel_launch(void* const* d_in, const int* in_sizes, int n_in,
                              void* d_out, int out_size, void* d_ws, size_t ws_size,
                              hipStream_t stream) {
    const float* feature = (const float*)d_in[0];
    const float* guide   = (const float*)d_in[1];
    const float* w1      = (const float*)d_in[2];
    const float* gamma   = (const float*)d_in[3];
    const float* beta    = (const float*)d_in[4];
    const float* mean    = (const float*)d_in[5];
    const float* var     = (const float*)d_in[6];
    const float* w2      = (const float*)d_in[7];
    const float* b2      = (const float*)d_in[8];
    float* out = (float*)d_out;

    bf16_t* xT = (bf16_t*)((char*)d_ws + XT_OFF);

    conv1_k<<<256, 512, 0, stream>>>(guide, w1, gamma, beta, mean, var, xT);
    fused_k<<<512, 256, 0, stream>>>(xT, w2, b2, feature, out);
}

// Round 8
// 125.819 us; speedup vs baseline: 1.1264x; 1.1264x over previous
//
#include <hip/hip_runtime.h>

// B=4, C=256, CR=64, H=W=64, K=7, KK=49, GROUPS=16, GC=16
#define BN_EPS 1e-5f

typedef __bf16 bf16_t;
typedef __bf16 bf16x8 __attribute__((ext_vector_type(8)));
typedef __bf16 bf16x4 __attribute__((ext_vector_type(4)));
typedef __bf16 bf16x2 __attribute__((ext_vector_type(2)));
typedef float  floatx4 __attribute__((ext_vector_type(4)));

#define MFMA16(a, b, c) __builtin_amdgcn_mfma_f32_16x16x32_bf16((a), (b), (c), 0, 0, 0)

// ws layout: only xT (16384 px x 64 ch bf16 = 2 MB)
#define XT_OFF 0

// ---------------------------------------------------------------------------
// K1 conv1: one block per (b,h), 512 threads (2 waves/SIMD). w1 A-frags direct
// from global (L2-hot) with BN fold in regs; guide transpose staged in LDS.
// MFMA x[64o][64p]; +bias, ReLU; store xT[bp][o] (c-contiguous).
// ---------------------------------------------------------------------------
#define GTP 264

__global__ __launch_bounds__(512) void conv1_k(
    const float* __restrict__ guide, const float* __restrict__ w1,
    const float* __restrict__ gamma, const float* __restrict__ beta,
    const float* __restrict__ mean,  const float* __restrict__ var,
    bf16_t* __restrict__ xT)
{
    __shared__ __attribute__((aligned(16))) bf16_t gTs[64 * GTP];  // 33.8 KB
    const int b = blockIdx.x >> 6, h = blockIdx.x & 63;
    const int t = threadIdx.x;

    // stage guide row transposed: coalesced dword reads (lanes = p)
    const float* gsrc = guide + (size_t)b * 256 * 4096 + h * 64;
#pragma unroll
    for (int i = 0; i < 16; ++i) {
        const int idx = i * 512 + t;       // 8192 units = 128 c2 x 64 p
        const int c2 = idx >> 6, p = idx & 63;
        const float g0 = gsrc[(size_t)(2 * c2) * 4096 + p];
        const float g1 = gsrc[(size_t)(2 * c2 + 1) * 4096 + p];
        bf16x2 pk; pk[0] = (bf16_t)g0; pk[1] = (bf16_t)g1;
        *(bf16x2*)&gTs[p * GTP + 2 * c2] = pk;
    }
    __syncthreads();

    const int wv = t >> 6, ln = t & 63, l15 = ln & 15, q = ln >> 4;
    const int ot = wv & 3;          // o-tile: channels ot*16 .. +16
    const int ph = wv >> 2;         // p-half: pixels ph*32 .. +32
    const int o = ot * 16 + l15;    // A-row this lane reads
    const float iv = gamma[o] * rsqrtf(var[o] + BN_EPS);

    floatx4 acc[2] = {};
#pragma unroll
    for (int ks = 0; ks < 8; ++ks) {
        const float* wp = w1 + o * 256 + ks * 32 + q * 8;
        const float4 a0 = *(const float4*)(wp);
        const float4 a1 = *(const float4*)(wp + 4);
        bf16x8 a;
        a[0] = (bf16_t)(a0.x * iv); a[1] = (bf16_t)(a0.y * iv);
        a[2] = (bf16_t)(a0.z * iv); a[3] = (bf16_t)(a0.w * iv);
        a[4] = (bf16_t)(a1.x * iv); a[5] = (bf16_t)(a1.y * iv);
        a[6] = (bf16_t)(a1.z * iv); a[7] = (bf16_t)(a1.w * iv);
#pragma unroll
        for (int nt = 0; nt < 2; ++nt) {
            const bf16x8 bb = *(const bf16x8*)&gTs[(ph * 32 + nt * 16 + l15) * GTP + ks * 32 + q * 8];
            acc[nt] = MFMA16(a, bb, acc[nt]);
        }
    }
    float bi[4];
#pragma unroll
    for (int j = 0; j < 4; ++j) {
        const int o2 = ot * 16 + q * 4 + j;
        const float iv2 = gamma[o2] * rsqrtf(var[o2] + BN_EPS);
        bi[j] = beta[o2] - mean[o2] * iv2;
    }
#pragma unroll
    for (int nt = 0; nt < 2; ++nt) {
        const int p = ph * 32 + nt * 16 + l15;
        bf16x4 v;
#pragma unroll
        for (int j = 0; j < 4; ++j) v[j] = (bf16_t)fmaxf(acc[nt][j] + bi[j], 0.f);
        *(bf16x4*)(xT + ((size_t)(b * 64 + h) * 64 + p) * 64 + ot * 16 + q * 4) = v;
    }
}

// ---------------------------------------------------------------------------
// K2 conv2+agg fused, 512-thr 4-ROW blocks: block = (g, b, h-quad), grid 1024.
// Inner structure = R6 verbatim per thread (same per-thread work, same VGPR
// shape ~100): phase0 stage-issue (6 f4 loads) -> phase1 MFMA (16/wave, 8
// waves cover 256 px) -> fs reg->LDS write -> ONE barrier -> depth-2
// pipelined agg. What changes: rounds 8 -> 2 (1024 blocks at 2/CU = 16
// waves/CU resident), fs staging redundancy 4x -> 2.5x.
// LDS = wgs 49x264 bf16 (25.9 KB) + fs 16x10x72 f32 (46.1 KB) = 72.0 KB
// -> exactly 2 blocks/CU. NO min-waves bound (R4: forced spill disaster).
// XCD = g%8 -> per-XCD feat slice ~2.1 MB + xT, L2-resident.
// ---------------------------------------------------------------------------
#define FSR 72      // fs row pitch (floats): [4 pad][64 w][4 pad]
#define FSC 720     // fs channel pitch = 10*72
#define WGP 264     // wgs row pitch (bf16): 256 px + 8 pad

__global__ __launch_bounds__(512) void fused_k(
    const bf16_t* __restrict__ xT, const float* __restrict__ w2,
    const float* __restrict__ b2,  const float* __restrict__ feat,
    float* __restrict__ out)
{
    __shared__ __attribute__((aligned(16))) float  fs[16 * FSC];   // 46.1 KB
    __shared__ __attribute__((aligned(16))) bf16_t wgs[49 * WGP];  // 25.9 KB

    const int g = blockIdx.x & 15;
    const int rest = blockIdx.x >> 4;      // 0..63
    const int b = rest >> 4, hq = rest & 15;
    const int h0 = hq * 4;
    const int t = threadIdx.x;
    const int wv = t >> 6, ln = t & 63, l15 = ln & 15, q = ln >> 4;

    // ---- phase0: ISSUE fs loads into regs (complete during MFMA phase) ----
    // 16 ch x 10 rows x 18 quads = 2880 quads, zero-padded borders
    float4 fsv[6];
    int    fsa[6];
#pragma unroll
    for (int i = 0; i < 6; ++i) {
        const int u = i * 512 + t;
        float4 v = {0.f, 0.f, 0.f, 0.f};
        int a = 0;
        if (u < 2880) {
            const int c = u / 180, rem = u - c * 180;
            const int rr = rem / 18, qq = rem - rr * 18;
            const int hh = h0 - 3 + rr;
            if (qq >= 1 && qq <= 16 && hh >= 0 && hh < 64)
                v = *(const float4*)(feat + ((size_t)(b * 256 + g * 16 + c) * 64 + hh) * 64 + (qq - 1) * 4);
            a = c * FSC + rr * FSR + qq * 4;
        }
        fsv[i] = v;
        fsa[i] = a;   // u>=2880 lanes write quad 0 of ch0/row0 (pad col, harmless)
    }

    // ---- phase1 MFMA: wg[49 x 256] = w2[g] . xT ; 8 waves x 32 px each ----
    {
        floatx4 acc[4][2] = {};
        // 256 px of this block are contiguous in xT: rows h0..h0+3
        const bf16_t* brow = xT + ((size_t)(b * 64 + h0) * 64 + wv * 32) * 64;
#pragma unroll
        for (int ks = 0; ks < 2; ++ks) {
            bf16x8 bfr[2];
            bfr[0] = *(const bf16x8*)(brow + l15 * 64 + ks * 32 + q * 8);
            bfr[1] = *(const bf16x8*)(brow + (16 + l15) * 64 + ks * 32 + q * 8);
#pragma unroll
            for (int mt = 0; mt < 4; ++mt) {
                int row = mt * 16 + l15; if (row > 48) row = 48;  // pad rows never stored
                const float* wp = w2 + (size_t)(g * 49 + row) * 64 + ks * 32 + q * 8;
                const float4 a0 = *(const float4*)(wp);
                const float4 a1 = *(const float4*)(wp + 4);
                bf16x8 a;
                a[0] = (bf16_t)a0.x; a[1] = (bf16_t)a0.y; a[2] = (bf16_t)a0.z; a[3] = (bf16_t)a0.w;
                a[4] = (bf16_t)a1.x; a[5] = (bf16_t)a1.y; a[6] = (bf16_t)a1.z; a[7] = (bf16_t)a1.w;
                acc[mt][0] = MFMA16(a, bfr[0], acc[mt][0]);
                acc[mt][1] = MFMA16(a, bfr[1], acc[mt][1]);
            }
        }
#pragma unroll
        for (int mt = 0; mt < 4; ++mt) {
#pragma unroll
            for (int j = 0; j < 4; ++j) {
                const int k = mt * 16 + q * 4 + j;
                if (k < 49) {
                    const float bias = b2[g * 49 + k];
                    wgs[k * WGP + wv * 32 + l15]      = (bf16_t)(acc[mt][0][j] + bias);
                    wgs[k * WGP + wv * 32 + 16 + l15] = (bf16_t)(acc[mt][1][j] + bias);
                }
            }
        }
    }

    // ---- write staged fs regs to LDS (loads completed under phase1) ----
#pragma unroll
    for (int i = 0; i < 6; ++i)
        *(float4*)&fs[fsa[i]] = fsv[i];
    __syncthreads();

    // ---- agg: thread = (wq, r in 0..3, cp) -> 2 ch x 4 w; depth-2 pipeline ----
    const int wq = t & 15, r = (t >> 4) & 3, cp = t >> 6;   // cp in [0,8)
    const int w0 = wq * 4;
    const int ch0 = cp * 2;

#define LOAD_STAGE(di, WA, FA, FB) do {                                        \
        const bf16_t* wrow_ = &wgs[((di) * 7) * WGP + r * 64 + w0];            \
        _Pragma("unroll")                                                      \
        for (int dj = 0; dj < 7; ++dj) WA[dj] = *(const bf16x4*)(wrow_ + dj * WGP); \
        const float* p0_ = &fs[ch0 * FSC + ((di) + r) * FSR + w0];             \
        const float* p1_ = p0_ + FSC;                                          \
        _Pragma("unroll")                                                      \
        for (int qj = 0; qj < 3; ++qj) {                                       \
            FA[qj] = *(const floatx4*)(p0_ + qj * 4);                          \
            FB[qj] = *(const floatx4*)(p1_ + qj * 4);                          \
        }                                                                      \
    } while (0)

#define FMA_STAGE(WA, FA, FB) do {                                             \
        _Pragma("unroll")                                                      \
        for (int dj = 0; dj < 7; ++dj) {                                       \
            const bf16x4 wb_ = WA[dj];                                         \
            _Pragma("unroll")                                                  \
            for (int x = 0; x < 4; ++x) {                                      \
                const int e = x + dj + 1;                                      \
                const float wf_ = (float)wb_[x];                               \
                acc[0][x] = fmaf(wf_, FA[e >> 2][e & 3], acc[0][x]);           \
                acc[1][x] = fmaf(wf_, FB[e >> 2][e & 3], acc[1][x]);           \
            }                                                                  \
        }                                                                      \
    } while (0)

    float acc[2][4] = {};
    bf16x4 waA[7], waB[7];
    floatx4 faA[3], fbA[3], faB[3], fbB[3];

    LOAD_STAGE(0, waA, faA, fbA);
    LOAD_STAGE(1, waB, faB, fbB);
    FMA_STAGE(waA, faA, fbA);
    LOAD_STAGE(2, waA, faA, fbA);
    FMA_STAGE(waB, faB, fbB);
    LOAD_STAGE(3, waB, faB, fbB);
    FMA_STAGE(waA, faA, fbA);
    LOAD_STAGE(4, waA, faA, fbA);
    FMA_STAGE(waB, faB, fbB);
    LOAD_STAGE(5, waB, faB, fbB);
    FMA_STAGE(waA, faA, fbA);
    LOAD_STAGE(6, waA, faA, fbA);
    FMA_STAGE(waB, faB, fbB);
    FMA_STAGE(waA, faA, fbA);

#undef LOAD_STAGE
#undef FMA_STAGE

    // residual from staged fp32 tile (row r+3 == h0+r), + store
#pragma unroll
    for (int c = 0; c < 2; ++c) {
        const floatx4 res = *(const floatx4*)&fs[(ch0 + c) * FSC + (r + 3) * FSR + 4 + w0];
        const size_t ob = ((size_t)(b * 256 + g * 16 + ch0 + c) * 64 + h0 + r) * 64 + w0;
        float4 o;
        o.x = acc[c][0] + res[0]; o.y = acc[c][1] + res[1];
        o.z = acc[c][2] + res[2]; o.w = acc[c][3] + res[3];
        *(float4*)(out + ob) = o;
    }
}

extern "C" void kernel_launch(void* const* d_in, const int* in_sizes, int n_in,
                              void* d_out, int out_size, void* d_ws, size_t ws_size,
                              hipStream_t stream) {
    const float* feature = (const float*)d_in[0];
    const float* guide   = (const float*)d_in[1];
    const float* w1      = (const float*)d_in[2];
    const float* gamma   = (const float*)d_in[3];
    const float* beta    = (const float*)d_in[4];
    const float* mean    = (const float*)d_in[5];
    const float* var     = (const float*)d_in[6];
    const float* w2      = (const float*)d_in[7];
    const float* b2      = (const float*)d_in[8];
    float* out = (float*)d_out;

    bf16_t* xT = (bf16_t*)((char*)d_ws + XT_OFF);

    conv1_k<<<256, 512, 0, stream>>>(guide, w1, gamma, beta, mean, var, xT);
    fused_k<<<1024, 512, 0, stream>>>(xT, w2, b2, feature, out);
}